// Round 2
// baseline (229.404 us; speedup 1.0000x reference)
//
#include <hip/hip_runtime.h>
#include <cmath>

#define NDEV   100000
#define NBATCH 8192
#define CONTF  62
#define EMB    16
#define FEAT   94      // 62 + 16 + 16
#define KNBR   64
#define NH     4
#define OUTD   16
#define HOUT   64      // NH*OUTD
#define FUS    204     // 94 + 94 + 16
#define ALPHA  0.2f

#define NDEVBLK 1563   // ceil(100000/64)
#define NCOMBBLK 128   // 8192/64

// ---------------- workspace layout (floats) ----------------
// h_d    : NDEV*64      = 6,400,000   @ 0
// e_d    : NDEV*4       =   400,000   @ 6,400,000
// combws : NBATCH*94    =   770,048   @ 6,800,000
// e_c    : NBATCH*4     =    32,768   @ 7,570,048
// fus8   : NBATCH*204   = 1,671,168   @ 7,602,816   (8-row interleaved)

// Per-lane row GEMM: acc[j] += x_f * W[f][j], j fully unrolled so acc stays
// in VGPRs (accumulators can't be rematerialized -> compiler must keep them).
// W accesses are wave-uniform (f is a uniform loop counter, j compile-time)
// -> scalar s_load on the SMEM pipe, overlapped with the 64 FMAs per f.
template <bool WRITE_X>
__device__ __forceinline__ void row_gemm(const float* __restrict__ crow,
                                         const float* __restrict__ e0,
                                         const float* __restrict__ e1,
                                         const float* __restrict__ W,
                                         const float* __restrict__ bias,
                                         float* __restrict__ xout,
                                         float acc[HOUT]) {
#pragma unroll
  for (int j = 0; j < HOUT; ++j) acc[j] = bias[j];

#pragma unroll 2
  for (int f = 0; f < CONTF; ++f) {
    const float x = crow[f];
    if (WRITE_X) xout[f] = x;
#pragma unroll
    for (int j = 0; j < HOUT; ++j)
      acc[j] = fmaf(x, W[(j >> 4) * (FEAT * OUTD) + f * OUTD + (j & 15)], acc[j]);
  }
#pragma unroll
  for (int t = 0; t < 4; ++t) {
    const float4 x4 = reinterpret_cast<const float4*>(e0)[t];
    const float xs[4] = {x4.x, x4.y, x4.z, x4.w};
#pragma unroll
    for (int c = 0; c < 4; ++c) {
      const int f = CONTF + 4 * t + c;
      if (WRITE_X) xout[f] = xs[c];
#pragma unroll
      for (int j = 0; j < HOUT; ++j)
        acc[j] = fmaf(xs[c], W[(j >> 4) * (FEAT * OUTD) + f * OUTD + (j & 15)], acc[j]);
    }
  }
#pragma unroll
  for (int t = 0; t < 4; ++t) {
    const float4 x4 = reinterpret_cast<const float4*>(e1)[t];
    const float xs[4] = {x4.x, x4.y, x4.z, x4.w};
#pragma unroll
    for (int c = 0; c < 4; ++c) {
      const int f = CONTF + EMB + 4 * t + c;
      if (WRITE_X) xout[f] = xs[c];
#pragma unroll
      for (int j = 0; j < HOUT; ++j)
        acc[j] = fmaf(xs[c], W[(j >> 4) * (FEAT * OUTD) + f * OUTD + (j & 15)], acc[j]);
    }
  }
}

// attention-logit partial: e[h] = sum_o acc[h*16+o] * aW[h*32 + aoff + o]
__device__ __forceinline__ float4 attn_logit(const float acc[HOUT],
                                             const float* __restrict__ aW,
                                             int aoff) {
  float ev[NH];
#pragma unroll
  for (int h = 0; h < NH; ++h) {
    float s = 0.f;
#pragma unroll
    for (int o = 0; o < OUTD; ++o)
      s = fmaf(acc[h * OUTD + o], aW[h * 2 * OUTD + aoff + o], s);
    ev[h] = s;
  }
  return make_float4(ev[0], ev[1], ev[2], ev[3]);
}

// ---------------- K1: per-device h_d/e_d AND per-row comb/e_c (fused) ------
__global__ __launch_bounds__(64) void k_feat(
    const float* __restrict__ device_cont, const int* __restrict__ device_cat,
    const float* __restrict__ de0, const float* __restrict__ de1,
    const float* __restrict__ Wd, const float* __restrict__ bd,
    const float* __restrict__ combin_cont, const int* __restrict__ combin_cat,
    const int* __restrict__ combin_idx,
    const float* __restrict__ ce0, const float* __restrict__ ce1,
    const float* __restrict__ Wc, const float* __restrict__ bc,
    const float* __restrict__ aW,
    float* __restrict__ h_d, float* __restrict__ e_d,
    float* __restrict__ combws, float* __restrict__ e_c) {
  const int blk = blockIdx.x;
  const int lane = threadIdx.x;

  if (blk < NDEVBLK) {
    // ---------- device path: lane = device ----------
    const int d = blk * 64 + lane;
    const int dc = d < NDEV ? d : NDEV - 1;
    const float* crow = device_cont + (size_t)dc * CONTF;
    const int c0 = device_cat[2 * dc], c1 = device_cat[2 * dc + 1];
    const float* e0 = de0 + c0 * EMB;
    const float* e1 = de1 + c1 * EMB;

    float acc[HOUT];
    row_gemm<false>(crow, e0, e1, Wd, bd, nullptr, acc);

    if (d < NDEV) {
      float4* hrow = reinterpret_cast<float4*>(h_d + (size_t)d * HOUT);
#pragma unroll
      for (int t = 0; t < 16; ++t)
        hrow[t] = make_float4(acc[4 * t], acc[4 * t + 1], acc[4 * t + 2], acc[4 * t + 3]);
      reinterpret_cast<float4*>(e_d)[d] = attn_logit(acc, aW, OUTD);  // a2
    }
  } else {
    // ---------- comb path: lane = batch row ----------
    const int b = (blk - NDEVBLK) * 64 + lane;
    const int ci = combin_idx[b];
    const float* crow = combin_cont + (size_t)ci * CONTF;
    const int c0 = combin_cat[2 * ci], c1 = combin_cat[2 * ci + 1];
    const float* e0 = ce0 + c0 * EMB;
    const float* e1 = ce1 + c1 * EMB;

    float acc[HOUT];
    row_gemm<true>(crow, e0, e1, Wc, bc, combws + (size_t)b * FEAT, acc);

    reinterpret_cast<float4*>(e_c)[b] = attn_logit(acc, aW, 0);  // a1
  }
}

// ---------------- K3: attention + fusion-row build ----------------
__global__ __launch_bounds__(256, 4) void k_attn(
    const int* __restrict__ neighbor_idx, const int* __restrict__ device_idx,
    const int* __restrict__ device_cat, const float* __restrict__ device_cont,
    const float* __restrict__ de0, const float* __restrict__ de1,
    const float* __restrict__ h_d, const float* __restrict__ e_d,
    const float* __restrict__ e_c, const float* __restrict__ ab,
    const float* __restrict__ W1, const float* __restrict__ b1,
    const float* __restrict__ combws, float* __restrict__ fus8) {
  __shared__ __align__(16) float pb[4][NH][68];  // 68: bank-spread padding
  __shared__ __align__(16) int   nb[4][KNBR];
  __shared__ float hb[4][HOUT];
  __shared__ float afb[4][OUTD];

  const int lane = threadIdx.x & 63;
  const int wid  = __builtin_amdgcn_readfirstlane((int)(threadIdx.x >> 6));
  const int b    = blockIdx.x * 4 + wid;

  // ---- phase 1: lane = neighbor k ----
  const int nk = neighbor_idx[(size_t)b * KNBR + lane];
  const float4 ed4 = *reinterpret_cast<const float4*>(e_d + (size_t)nk * NH);
  const float4 ec4 = *reinterpret_cast<const float4*>(e_c + (size_t)b * NH);
  const float4 ab4 = *reinterpret_cast<const float4*>(ab);

  float v0 = ec4.x + ed4.x + ab4.x;
  float v1 = ec4.y + ed4.y + ab4.y;
  float v2 = ec4.z + ed4.z + ab4.z;
  float v3 = ec4.w + ed4.w + ab4.w;
  v0 = v0 > 0.f ? v0 : ALPHA * v0;
  v1 = v1 > 0.f ? v1 : ALPHA * v1;
  v2 = v2 > 0.f ? v2 : ALPHA * v2;
  v3 = v3 > 0.f ? v3 : ALPHA * v3;

  float m0 = v0, m1 = v1, m2 = v2, m3 = v3;
#pragma unroll
  for (int msk = 1; msk < 64; msk <<= 1) {
    m0 = fmaxf(m0, __shfl_xor(m0, msk));
    m1 = fmaxf(m1, __shfl_xor(m1, msk));
    m2 = fmaxf(m2, __shfl_xor(m2, msk));
    m3 = fmaxf(m3, __shfl_xor(m3, msk));
  }
  float p0 = expf(v0 - m0), p1 = expf(v1 - m1), p2 = expf(v2 - m2), p3 = expf(v3 - m3);
  float s0 = p0, s1 = p1, s2 = p2, s3 = p3;
#pragma unroll
  for (int msk = 1; msk < 64; msk <<= 1) {
    s0 += __shfl_xor(s0, msk);
    s1 += __shfl_xor(s1, msk);
    s2 += __shfl_xor(s2, msk);
    s3 += __shfl_xor(s3, msk);
  }
  p0 /= s0; p1 /= s1; p2 /= s2; p3 /= s3;

  pb[wid][0][lane] = p0;
  pb[wid][1][lane] = p1;
  pb[wid][2][lane] = p2;
  pb[wid][3][lane] = p3;
  nb[wid][lane]    = nk;
  __syncthreads();

  // ---- phase 2: lane = (h,o) ----
  const int h = lane >> 4;  // head
  float acc = 0.f;
#pragma unroll
  for (int j = 0; j < 16; ++j) {
    const float4 p4 = *reinterpret_cast<const float4*>(&pb[wid][h][4 * j]);
    const int4   n4 = *reinterpret_cast<const int4*>(&nb[wid][4 * j]);
    acc = fmaf(p4.x, h_d[(size_t)n4.x * HOUT + lane], acc);
    acc = fmaf(p4.y, h_d[(size_t)n4.y * HOUT + lane], acc);
    acc = fmaf(p4.z, h_d[(size_t)n4.z * HOUT + lane], acc);
    acc = fmaf(p4.w, h_d[(size_t)n4.w * HOUT + lane], acc);
  }
  const float ho = acc > 0.f ? acc : expm1f(acc);  // elu
  hb[wid][lane] = ho;
  __syncthreads();

  // ---- attn_feats = head_out(64) @ W1(64x16) + b1 ----
  {
    const int j = lane & 15, g = lane >> 4;
    float part = 0.f;
#pragma unroll
    for (int t = 0; t < 16; ++t)
      part = fmaf(hb[wid][g * 16 + t], W1[(g * 16 + t) * OUTD + j], part);
    part += __shfl_xor(part, 16);
    part += __shfl_xor(part, 32);
    if (lane < 16) afb[wid][lane] = part + b1[lane];
  }
  __syncthreads();

  // ---- write fusion row: [comb 94 | dev 94 | att 16] 8-row interleaved ----
  const int didx = device_idx[b];
  const int dc0 = device_cat[2 * didx], dc1 = device_cat[2 * didx + 1];
  float* base = fus8 + (size_t)(b >> 3) * (FUS * 8) + (b & 7);
#pragma unroll
  for (int t = 0; t < 4; ++t) {
    const int i = lane + t * 64;
    if (i < FUS) {
      float v;
      if (i < 94)       v = combws[(size_t)b * FEAT + i];
      else if (i < 156) v = device_cont[(size_t)didx * CONTF + (i - 94)];
      else if (i < 172) v = de0[dc0 * EMB + (i - 156)];
      else if (i < 188) v = de1[dc1 * EMB + (i - 172)];
      else              v = afb[wid][i - 188];
      base[(size_t)i * 8] = v;
    }
  }
}

// ---------------- K4: MLP (fusion 204 -> 64 -> 32 -> 1) ----------------
__global__ __launch_bounds__(256, 2) void k_mlp(
    const float* __restrict__ fus8,
    const float* __restrict__ W2, const float* __restrict__ b2,
    const float* __restrict__ W3, const float* __restrict__ b3,
    const float* __restrict__ W4, const float* __restrict__ b4,
    float* __restrict__ out) {
  __shared__ __align__(16) float x1b[4][8][64];
  const int lane = threadIdx.x & 63;
  const int wid  = __builtin_amdgcn_readfirstlane((int)(threadIdx.x >> 6));
  const int g    = blockIdx.x * 4 + wid;  // row-group of 8
  const float* fg = fus8 + (size_t)g * (FUS * 8);

  float acc[8];
  const float bj = b2[lane];
#pragma unroll
  for (int r = 0; r < 8; ++r) acc[r] = bj;

#pragma unroll 4
  for (int i = 0; i < FUS; ++i) {
    const float wv = W2[i * 64 + lane];       // lane = x1 column
    const float* fr = fg + i * 8;             // wave-uniform -> s_load
#pragma unroll
    for (int r = 0; r < 8; ++r) acc[r] = fmaf(fr[r], wv, acc[r]);
  }
#pragma unroll
  for (int r = 0; r < 8; ++r) x1b[wid][r][lane] = fmaxf(acc[r], 0.f);
  __syncthreads();

  const int m = lane & 31, rh = lane >> 5;    // rh picks rows 0-3 / 4-7
  float x2[4];
#pragma unroll
  for (int r = 0; r < 4; ++r) x2[r] = b3[m];
#pragma unroll 4
  for (int j4 = 0; j4 < 16; ++j4) {
    float w30 = W3[(4 * j4 + 0) * 32 + m];
    float w31 = W3[(4 * j4 + 1) * 32 + m];
    float w32 = W3[(4 * j4 + 2) * 32 + m];
    float w33 = W3[(4 * j4 + 3) * 32 + m];
#pragma unroll
    for (int r = 0; r < 4; ++r) {
      const float4 xv = *reinterpret_cast<const float4*>(&x1b[wid][rh * 4 + r][4 * j4]);
      x2[r] = fmaf(xv.x, w30, x2[r]);
      x2[r] = fmaf(xv.y, w31, x2[r]);
      x2[r] = fmaf(xv.z, w32, x2[r]);
      x2[r] = fmaf(xv.w, w33, x2[r]);
    }
  }
  const float w4 = W4[m];
  float part[4];
#pragma unroll
  for (int r = 0; r < 4; ++r) part[r] = fmaxf(x2[r], 0.f) * w4;
#pragma unroll
  for (int msk = 1; msk < 32; msk <<= 1) {
#pragma unroll
    for (int r = 0; r < 4; ++r) part[r] += __shfl_xor(part[r], msk);
  }
  if (m == 0) {
    const float bb = b4[0];
#pragma unroll
    for (int r = 0; r < 4; ++r) {
      const float z = part[r] + bb;
      out[(size_t)g * 8 + rh * 4 + r] = 1.f / (1.f + expf(-z));
    }
  }
}

extern "C" void kernel_launch(void* const* d_in, const int* in_sizes, int n_in,
                              void* d_out, int out_size, void* d_ws, size_t ws_size,
                              hipStream_t stream) {
  const float* combin_cont  = (const float*)d_in[0];
  const int*   combin_cat   = (const int*)d_in[1];
  const float* device_cont  = (const float*)d_in[2];
  const int*   device_cat   = (const int*)d_in[3];
  const int*   combin_idx   = (const int*)d_in[4];
  const int*   device_idx   = (const int*)d_in[5];
  const int*   neighbor_idx = (const int*)d_in[6];
  const float* ce0 = (const float*)d_in[7];
  const float* ce1 = (const float*)d_in[8];
  const float* de0 = (const float*)d_in[9];
  const float* de1 = (const float*)d_in[10];
  const float* Wc  = (const float*)d_in[11];
  const float* bc  = (const float*)d_in[12];
  const float* Wd  = (const float*)d_in[13];
  const float* bd  = (const float*)d_in[14];
  const float* aW  = (const float*)d_in[15];
  const float* ab  = (const float*)d_in[16];
  const float* W1  = (const float*)d_in[17];
  const float* b1  = (const float*)d_in[18];
  const float* W2  = (const float*)d_in[19];
  const float* b2  = (const float*)d_in[20];
  const float* W3  = (const float*)d_in[21];
  const float* b3  = (const float*)d_in[22];
  const float* W4  = (const float*)d_in[23];
  const float* b4  = (const float*)d_in[24];

  float* ws     = (float*)d_ws;
  float* h_d    = ws;
  float* e_d    = ws + 6400000;
  float* combws = ws + 6800000;
  float* e_c    = ws + 7570048;
  float* fus8   = ws + 7602816;

  k_feat<<<NDEVBLK + NCOMBBLK, 64, 0, stream>>>(
      device_cont, device_cat, de0, de1, Wd, bd,
      combin_cont, combin_cat, combin_idx, ce0, ce1, Wc, bc, aW,
      h_d, e_d, combws, e_c);
  k_attn<<<2048, 256, 0, stream>>>(neighbor_idx, device_idx, device_cat, device_cont, de0, de1,
                                   h_d, e_d, e_c, ab, W1, b1, combws, fus8);
  k_mlp<<<256, 256, 0, stream>>>(fus8, W2, b2, W3, b3, W4, b4, (float*)d_out);
}

// Round 3
// 200.411 us; speedup vs baseline: 1.1447x; 1.1447x over previous
//
#include <hip/hip_runtime.h>
#include <cmath>

#define NDEV   100000
#define NBATCH 8192
#define CONTF  62
#define EMB    16
#define FEAT   94      // 62 + 16 + 16
#define KNBR   64
#define NH     4
#define OUTD   16
#define HOUT   64      // NH*OUTD
#define FUS    204     // 94 + 94 + 16
#define ALPHA  0.2f

#define MTILE   128
#define XSTRIDE 132    // MTILE+4: keeps f-rows 16B aligned (132*4 % 16 == 0), gcd(4,32) conflicts 2-way only
#define NDEVBLK2 782   // ceil(100000/128)
#define NCOMBBLK2 64   // 8192/128

// ---------------- workspace layout (floats) ----------------
// h_d    : NDEV*64      = 6,400,000   @ 0
// e_d    : NDEV*4       =   400,000   @ 6,400,000
// combws : NBATCH*94    =   770,048   @ 6,800,000
// e_c    : NBATCH*4     =    32,768   @ 7,570,048
// fus8   : NBATCH*204   = 1,671,168   @ 7,602,816   (8-row interleaved)

// ---------------- K1: tiled GEMM  X[rows x 94] @ W[94 x 64]  ----------------
// Per block: 128 rows staged transposed in LDS + whole W in LDS.
// Wave w: rowblk=w>>1 (64 rows), colblk=w&1 (32 cols). Lane: mr=lane>>3 (8 rows), nr=lane&7 (4 cols).
__global__ __launch_bounds__(256, 2) void k_feat(
    const float* __restrict__ device_cont, const int* __restrict__ device_cat,
    const float* __restrict__ de0, const float* __restrict__ de1,
    const float* __restrict__ Wd, const float* __restrict__ bd,
    const float* __restrict__ combin_cont, const int* __restrict__ combin_cat,
    const int* __restrict__ combin_idx,
    const float* __restrict__ ce0, const float* __restrict__ ce1,
    const float* __restrict__ Wc, const float* __restrict__ bc,
    const float* __restrict__ aW,
    float* __restrict__ h_d, float* __restrict__ e_d,
    float* __restrict__ combws, float* __restrict__ e_c) {
  __shared__ float x_lds[FEAT * XSTRIDE];   // 49,632 B  [f][row]
  __shared__ float w_lds[FEAT * HOUT];      // 24,064 B  [f][col]
  __shared__ int   idx_lds[MTILE];

  const int tid = threadIdx.x;
  const int blk = blockIdx.x;
  const bool devpath = blk < NDEVBLK2;
  const int b0 = devpath ? blk * MTILE : (blk - NDEVBLK2) * MTILE;

  // ---- stage W (linear copy, 1504 float4) ----
  const float* __restrict__ W = devpath ? Wd : Wc;
  for (int i = tid; i < (FEAT * HOUT) / 4; i += 256)
    reinterpret_cast<float4*>(w_lds)[i] = reinterpret_cast<const float4*>(W)[i];

  // ---- stage row indices (comb path) ----
  if (!devpath && tid < MTILE) idx_lds[tid] = combin_idx[b0 + tid];
  __syncthreads();

  // ---- stage X transposed: 2 threads per row, 47+? split via halves ----
  {
    const int row = tid >> 1, half = tid & 1;
    const int src = devpath ? min(b0 + row, NDEV - 1) : idx_lds[row];
    const float* __restrict__ cont = devpath ? device_cont : combin_cont;
    const int*   __restrict__ cat  = devpath ? device_cat : combin_cat;
    const float* __restrict__ crow = cont + (size_t)src * CONTF + half * 31;
    float* __restrict__ xcol = x_lds + row;
#pragma unroll
    for (int k = 0; k < 31; ++k)
      xcol[(half * 31 + k) * XSTRIDE] = crow[k];
    const int cidx = cat[2 * src + half];
    const float* __restrict__ erow =
        (half ? (devpath ? de1 : ce1) : (devpath ? de0 : ce0)) + cidx * EMB;
#pragma unroll
    for (int k4 = 0; k4 < 4; ++k4) {
      const float4 ev = reinterpret_cast<const float4*>(erow)[k4];
      const int fb = CONTF + half * EMB + k4 * 4;
      xcol[(fb + 0) * XSTRIDE] = ev.x;
      xcol[(fb + 1) * XSTRIDE] = ev.y;
      xcol[(fb + 2) * XSTRIDE] = ev.z;
      xcol[(fb + 3) * XSTRIDE] = ev.w;
    }
  }
  __syncthreads();

  // ---- comb path: spill comb_batch rows to combws (needed for fusion later) ----
  if (!devpath) {
    const int row = tid >> 1, half = tid & 1;
    float* __restrict__ dst = combws + (size_t)(b0 + row) * FEAT + half * 47;
    const float* __restrict__ srcc = x_lds + row;
#pragma unroll
    for (int k = 0; k < 47; ++k)
      dst[k] = srcc[(half * 47 + k) * XSTRIDE];
  }

  // ---- compute: 8x4 register tile per lane ----
  const int wid    = tid >> 6;
  const int lane   = tid & 63;
  const int rowblk = wid >> 1, colblk = wid & 1;
  const int mr = lane >> 3, nr = lane & 7;
  const int r0 = rowblk * 64 + mr * 8;
  const int c0 = colblk * 32 + nr * 4;

  const float4 bi = reinterpret_cast<const float4*>(devpath ? bd : bc)[c0 >> 2];
  float acc[8][4];
#pragma unroll
  for (int r = 0; r < 8; ++r) {
    acc[r][0] = bi.x; acc[r][1] = bi.y; acc[r][2] = bi.z; acc[r][3] = bi.w;
  }

#pragma unroll 2
  for (int f = 0; f < FEAT; ++f) {
    const float4 xa = *reinterpret_cast<const float4*>(&x_lds[f * XSTRIDE + r0]);
    const float4 xb = *reinterpret_cast<const float4*>(&x_lds[f * XSTRIDE + r0 + 4]);
    const float4 wv = *reinterpret_cast<const float4*>(&w_lds[f * HOUT + c0]);
    const float xs[8] = {xa.x, xa.y, xa.z, xa.w, xb.x, xb.y, xb.z, xb.w};
#pragma unroll
    for (int r = 0; r < 8; ++r) {
      acc[r][0] = fmaf(xs[r], wv.x, acc[r][0]);
      acc[r][1] = fmaf(xs[r], wv.y, acc[r][1]);
      acc[r][2] = fmaf(xs[r], wv.z, acc[r][2]);
      acc[r][3] = fmaf(xs[r], wv.w, acc[r][3]);
    }
  }

  // ---- epilogue ----
  const int h = (c0 >> 4);                       // head for these 4 cols
  const int aoff = devpath ? OUTD : 0;           // a2 for devices, a1 for comb
  const float4 av = *reinterpret_cast<const float4*>(&aW[h * 2 * OUTD + aoff + (c0 & 15)]);
  float* __restrict__ eout = devpath ? e_d : e_c;

#pragma unroll
  for (int r = 0; r < 8; ++r) {
    const int gr = b0 + r0 + r;
    const bool valid = devpath ? (gr < NDEV) : true;
    if (devpath && valid) {
      float4 o4 = make_float4(acc[r][0], acc[r][1], acc[r][2], acc[r][3]);
      *reinterpret_cast<float4*>(&h_d[(size_t)gr * HOUT + c0]) = o4;
    }
    float s = acc[r][0] * av.x + acc[r][1] * av.y + acc[r][2] * av.z + acc[r][3] * av.w;
    s += __shfl_xor(s, 1);
    s += __shfl_xor(s, 2);
    if ((lane & 3) == 0 && valid)
      eout[(size_t)gr * NH + h] = s;
  }
}

// ---------------- K3: attention + fusion-row build ----------------
__global__ __launch_bounds__(256, 4) void k_attn(
    const int* __restrict__ neighbor_idx, const int* __restrict__ device_idx,
    const int* __restrict__ device_cat, const float* __restrict__ device_cont,
    const float* __restrict__ de0, const float* __restrict__ de1,
    const float* __restrict__ h_d, const float* __restrict__ e_d,
    const float* __restrict__ e_c, const float* __restrict__ ab,
    const float* __restrict__ W1, const float* __restrict__ b1,
    const float* __restrict__ combws, float* __restrict__ fus8) {
  __shared__ __align__(16) float pb[4][NH][68];
  __shared__ __align__(16) int   nb[4][KNBR];
  __shared__ float hb[4][HOUT];
  __shared__ float afb[4][OUTD];

  const int lane = threadIdx.x & 63;
  const int wid  = __builtin_amdgcn_readfirstlane((int)(threadIdx.x >> 6));
  const int b    = blockIdx.x * 4 + wid;

  const int nk = neighbor_idx[(size_t)b * KNBR + lane];
  const float4 ed4 = *reinterpret_cast<const float4*>(e_d + (size_t)nk * NH);
  const float4 ec4 = *reinterpret_cast<const float4*>(e_c + (size_t)b * NH);
  const float4 ab4 = *reinterpret_cast<const float4*>(ab);

  float v0 = ec4.x + ed4.x + ab4.x;
  float v1 = ec4.y + ed4.y + ab4.y;
  float v2 = ec4.z + ed4.z + ab4.z;
  float v3 = ec4.w + ed4.w + ab4.w;
  v0 = v0 > 0.f ? v0 : ALPHA * v0;
  v1 = v1 > 0.f ? v1 : ALPHA * v1;
  v2 = v2 > 0.f ? v2 : ALPHA * v2;
  v3 = v3 > 0.f ? v3 : ALPHA * v3;

  float m0 = v0, m1 = v1, m2 = v2, m3 = v3;
#pragma unroll
  for (int msk = 1; msk < 64; msk <<= 1) {
    m0 = fmaxf(m0, __shfl_xor(m0, msk));
    m1 = fmaxf(m1, __shfl_xor(m1, msk));
    m2 = fmaxf(m2, __shfl_xor(m2, msk));
    m3 = fmaxf(m3, __shfl_xor(m3, msk));
  }
  float p0 = expf(v0 - m0), p1 = expf(v1 - m1), p2 = expf(v2 - m2), p3 = expf(v3 - m3);
  float s0 = p0, s1 = p1, s2 = p2, s3 = p3;
#pragma unroll
  for (int msk = 1; msk < 64; msk <<= 1) {
    s0 += __shfl_xor(s0, msk);
    s1 += __shfl_xor(s1, msk);
    s2 += __shfl_xor(s2, msk);
    s3 += __shfl_xor(s3, msk);
  }
  p0 /= s0; p1 /= s1; p2 /= s2; p3 /= s3;

  pb[wid][0][lane] = p0;
  pb[wid][1][lane] = p1;
  pb[wid][2][lane] = p2;
  pb[wid][3][lane] = p3;
  nb[wid][lane]    = nk;
  __syncthreads();

  const int h = lane >> 4;
  float acc = 0.f;
#pragma unroll
  for (int j = 0; j < 16; ++j) {
    const float4 p4 = *reinterpret_cast<const float4*>(&pb[wid][h][4 * j]);
    const int4   n4 = *reinterpret_cast<const int4*>(&nb[wid][4 * j]);
    acc = fmaf(p4.x, h_d[(size_t)n4.x * HOUT + lane], acc);
    acc = fmaf(p4.y, h_d[(size_t)n4.y * HOUT + lane], acc);
    acc = fmaf(p4.z, h_d[(size_t)n4.z * HOUT + lane], acc);
    acc = fmaf(p4.w, h_d[(size_t)n4.w * HOUT + lane], acc);
  }
  const float ho = acc > 0.f ? acc : expm1f(acc);
  hb[wid][lane] = ho;
  __syncthreads();

  {
    const int j = lane & 15, g = lane >> 4;
    float part = 0.f;
#pragma unroll
    for (int t = 0; t < 16; ++t)
      part = fmaf(hb[wid][g * 16 + t], W1[(g * 16 + t) * OUTD + j], part);
    part += __shfl_xor(part, 16);
    part += __shfl_xor(part, 32);
    if (lane < 16) afb[wid][lane] = part + b1[lane];
  }
  __syncthreads();

  const int didx = device_idx[b];
  const int dc0 = device_cat[2 * didx], dc1 = device_cat[2 * didx + 1];
  float* base = fus8 + (size_t)(b >> 3) * (FUS * 8) + (b & 7);
#pragma unroll
  for (int t = 0; t < 4; ++t) {
    const int i = lane + t * 64;
    if (i < FUS) {
      float v;
      if (i < 94)       v = combws[(size_t)b * FEAT + i];
      else if (i < 156) v = device_cont[(size_t)didx * CONTF + (i - 94)];
      else if (i < 172) v = de0[dc0 * EMB + (i - 156)];
      else if (i < 188) v = de1[dc1 * EMB + (i - 172)];
      else              v = afb[wid][i - 188];
      base[(size_t)i * 8] = v;
    }
  }
}

// ---------------- K4: MLP (fusion 204 -> 64 -> 32 -> 1) ----------------
__global__ __launch_bounds__(256, 2) void k_mlp(
    const float* __restrict__ fus8,
    const float* __restrict__ W2, const float* __restrict__ b2,
    const float* __restrict__ W3, const float* __restrict__ b3,
    const float* __restrict__ W4, const float* __restrict__ b4,
    float* __restrict__ out) {
  __shared__ __align__(16) float x1b[4][8][64];
  const int lane = threadIdx.x & 63;
  const int wid  = __builtin_amdgcn_readfirstlane((int)(threadIdx.x >> 6));
  const int g    = blockIdx.x * 4 + wid;
  const float* fg = fus8 + (size_t)g * (FUS * 8);

  float acc[8];
  const float bj = b2[lane];
#pragma unroll
  for (int r = 0; r < 8; ++r) acc[r] = bj;

#pragma unroll 4
  for (int i = 0; i < FUS; ++i) {
    const float wv = W2[i * 64 + lane];
    const float* fr = fg + i * 8;
#pragma unroll
    for (int r = 0; r < 8; ++r) acc[r] = fmaf(fr[r], wv, acc[r]);
  }
#pragma unroll
  for (int r = 0; r < 8; ++r) x1b[wid][r][lane] = fmaxf(acc[r], 0.f);
  __syncthreads();

  const int m = lane & 31, rh = lane >> 5;
  float x2[4];
#pragma unroll
  for (int r = 0; r < 4; ++r) x2[r] = b3[m];
#pragma unroll 4
  for (int j4 = 0; j4 < 16; ++j4) {
    float w30 = W3[(4 * j4 + 0) * 32 + m];
    float w31 = W3[(4 * j4 + 1) * 32 + m];
    float w32 = W3[(4 * j4 + 2) * 32 + m];
    float w33 = W3[(4 * j4 + 3) * 32 + m];
#pragma unroll
    for (int r = 0; r < 4; ++r) {
      const float4 xv = *reinterpret_cast<const float4*>(&x1b[wid][rh * 4 + r][4 * j4]);
      x2[r] = fmaf(xv.x, w30, x2[r]);
      x2[r] = fmaf(xv.y, w31, x2[r]);
      x2[r] = fmaf(xv.z, w32, x2[r]);
      x2[r] = fmaf(xv.w, w33, x2[r]);
    }
  }
  const float w4 = W4[m];
  float part[4];
#pragma unroll
  for (int r = 0; r < 4; ++r) part[r] = fmaxf(x2[r], 0.f) * w4;
#pragma unroll
  for (int msk = 1; msk < 32; msk <<= 1) {
#pragma unroll
    for (int r = 0; r < 4; ++r) part[r] += __shfl_xor(part[r], msk);
  }
  if (m == 0) {
    const float bb = b4[0];
#pragma unroll
    for (int r = 0; r < 4; ++r) {
      const float z = part[r] + bb;
      out[(size_t)g * 8 + rh * 4 + r] = 1.f / (1.f + expf(-z));
    }
  }
}

extern "C" void kernel_launch(void* const* d_in, const int* in_sizes, int n_in,
                              void* d_out, int out_size, void* d_ws, size_t ws_size,
                              hipStream_t stream) {
  const float* combin_cont  = (const float*)d_in[0];
  const int*   combin_cat   = (const int*)d_in[1];
  const float* device_cont  = (const float*)d_in[2];
  const int*   device_cat   = (const int*)d_in[3];
  const int*   combin_idx   = (const int*)d_in[4];
  const int*   device_idx   = (const int*)d_in[5];
  const int*   neighbor_idx = (const int*)d_in[6];
  const float* ce0 = (const float*)d_in[7];
  const float* ce1 = (const float*)d_in[8];
  const float* de0 = (const float*)d_in[9];
  const float* de1 = (const float*)d_in[10];
  const float* Wc  = (const float*)d_in[11];
  const float* bc  = (const float*)d_in[12];
  const float* Wd  = (const float*)d_in[13];
  const float* bd  = (const float*)d_in[14];
  const float* aW  = (const float*)d_in[15];
  const float* ab  = (const float*)d_in[16];
  const float* W1  = (const float*)d_in[17];
  const float* b1  = (const float*)d_in[18];
  const float* W2  = (const float*)d_in[19];
  const float* b2  = (const float*)d_in[20];
  const float* W3  = (const float*)d_in[21];
  const float* b3  = (const float*)d_in[22];
  const float* W4  = (const float*)d_in[23];
  const float* b4  = (const float*)d_in[24];

  float* ws     = (float*)d_ws;
  float* h_d    = ws;
  float* e_d    = ws + 6400000;
  float* combws = ws + 6800000;
  float* e_c    = ws + 7570048;
  float* fus8   = ws + 7602816;

  k_feat<<<NDEVBLK2 + NCOMBBLK2, 256, 0, stream>>>(
      device_cont, device_cat, de0, de1, Wd, bd,
      combin_cont, combin_cat, combin_idx, ce0, ce1, Wc, bc, aW,
      h_d, e_d, combws, e_c);
  k_attn<<<2048, 256, 0, stream>>>(neighbor_idx, device_idx, device_cat, device_cont, de0, de1,
                                   h_d, e_d, e_c, ab, W1, b1, combws, fus8);
  k_mlp<<<256, 256, 0, stream>>>(fus8, W2, b2, W3, b3, W4, b4, (float*)d_out);
}